// Round 4
// baseline (289.858 us; speedup 1.0000x reference)
//
#include <hip/hip_runtime.h>
#include <cstddef>
#include <cstdint>

#define B_DIM   2
#define S_LEN   2048
#define EMB     1024
#define NH      16
#define HD      64
#define QKV_N   3072
#define MROWS   (B_DIM * S_LEN)

using half8  = __attribute__((ext_vector_type(8))) _Float16;
using half4  = __attribute__((ext_vector_type(4))) _Float16;
using f32x4  = __attribute__((ext_vector_type(4))) float;

#if defined(__has_builtin)
#if __has_builtin(__builtin_amdgcn_global_load_lds)
#define HAS_GLL 1
#endif
#endif

__device__ __forceinline__ void stage16(const _Float16* g, _Float16* lds_base, int lane)
{
#ifdef HAS_GLL
    (void)lane;
    __builtin_amdgcn_global_load_lds(
        (const __attribute__((address_space(1))) unsigned int*)g,
        (__attribute__((address_space(3))) unsigned int*)lds_base, 16, 0, 0);
#else
    *(half8*)(lds_base + lane * 8) = *(const half8*)g;
#endif
}

// ---------------------------------------------------------------------------
// Merged prep: [0,4096) cast hidden; [4096,7168) transpose w_attn;
// [7168,8192) transpose w_proj.
// ---------------------------------------------------------------------------
__global__ __launch_bounds__(256)
void prep_all(const float* __restrict__ hidden, const float* __restrict__ w_attn,
              const float* __restrict__ w_proj, _Float16* __restrict__ hidden_h,
              _Float16* __restrict__ wattn_t, _Float16* __restrict__ wproj_t)
{
    const int bid = blockIdx.x, t = threadIdx.x;
    if (bid < 4096) {
        int i = bid * 1024 + t * 4;
        float4 v = *(const float4*)(hidden + i);
        half4 h = { (_Float16)v.x, (_Float16)v.y, (_Float16)v.z, (_Float16)v.w };
        *(half4*)(hidden_h + i) = h;
        return;
    }
    __shared__ float T[32][33];
    const float* W; _Float16* Wt; int N, bx, by;
    if (bid < 7168) {
        int t2 = bid - 4096; bx = t2 % 96; by = t2 / 96; W = w_attn; Wt = wattn_t; N = QKV_N;
    } else {
        int t3 = bid - 7168; bx = t3 & 31; by = t3 >> 5; W = w_proj; Wt = wproj_t; N = EMB;
    }
    const int n0 = bx * 32, k0 = by * 32;
    const int r = t >> 3, c4 = (t & 7) * 4;
    float4 w = *(const float4*)(W + (size_t)(k0 + r) * N + n0 + c4);
    T[r][c4 + 0] = w.x; T[r][c4 + 1] = w.y;
    T[r][c4 + 2] = w.z; T[r][c4 + 3] = w.w;
    __syncthreads();
    half4 h = { (_Float16)T[c4 + 0][r], (_Float16)T[c4 + 1][r],
                (_Float16)T[c4 + 2][r], (_Float16)T[c4 + 3][r] };
    *(half4*)(Wt + (size_t)(n0 + r) * EMB + k0 + c4) = h;
}

// ---------------------------------------------------------------------------
// f16 MFMA GEMM, BK=64, GLL staging, XOR-swizzled LDS columns.
// FUSE_VT: blocks with n0 >= 2*EMB write V transposed into vt[bh][d][s].
// ---------------------------------------------------------------------------
template <int MT, int MINW, bool OUT_F16, bool FUSE_VT>
__global__ __launch_bounds__(256, MINW)
void hgemm_lds(const _Float16* __restrict__ X, const _Float16* __restrict__ Wt,
               const float* __restrict__ bias, void* __restrict__ Cout,
               _Float16* __restrict__ vt, int M, int N, int K)
{
    constexpr int BM = MT * 32;
    constexpr int ACALLS = BM / 32;
    __shared__ _Float16 As[BM][64];
    __shared__ _Float16 Bs[128][64];

    const int tid  = threadIdx.x;
    const int wave = tid >> 6, lane = tid & 63;
    const int quad = lane >> 4, l15 = lane & 15;
    const int wm = (wave >> 1) * (MT * 16);
    const int wn = (wave & 1) * 64;
    const int m0 = blockIdx.y * BM, n0 = blockIdx.x * 128;

    const int srow = lane >> 3;
    const int scol = ((lane & 7) ^ srow) * 8;

    const _Float16* xg[ACALLS];
#pragma unroll
    for (int c = 0; c < ACALLS; ++c)
        xg[c] = X + (size_t)(m0 + wave * (BM / 4) + c * 8 + srow) * K + scol;
    const _Float16* wg[4];
#pragma unroll
    for (int c = 0; c < 4; ++c)
        wg[c] = Wt + (size_t)(n0 + wave * 32 + c * 8 + srow) * K + scol;

    f32x4 acc[MT][4] = {};
    const int sx = l15 & 7;

    for (int k0 = 0; k0 < K; k0 += 64) {
#pragma unroll
        for (int c = 0; c < ACALLS; ++c)
            stage16(xg[c] + k0, &As[wave * (BM / 4) + c * 8][0], lane);
#pragma unroll
        for (int c = 0; c < 4; ++c)
            stage16(wg[c] + k0, &Bs[wave * 32 + c * 8][0], lane);
        __syncthreads();

#pragma unroll
        for (int cc = 0; cc < 2; ++cc) {
            half8 af[MT], bf[4];
#pragma unroll
            for (int mt = 0; mt < MT; ++mt)
                af[mt] = *(const half8*)&As[wm + mt * 16 + l15][(((cc * 4 + quad) ^ sx)) * 8];
#pragma unroll
            for (int nt = 0; nt < 4; ++nt)
                bf[nt] = *(const half8*)&Bs[wn + nt * 16 + l15][(((cc * 4 + quad) ^ sx)) * 8];
#pragma unroll
            for (int mt = 0; mt < MT; ++mt)
#pragma unroll
                for (int nt = 0; nt < 4; ++nt)
                    acc[mt][nt] = __builtin_amdgcn_mfma_f32_16x16x32_f16(
                        af[mt], bf[nt], acc[mt][nt], 0, 0, 0);
        }
        __syncthreads();
    }

    if (FUSE_VT && n0 >= 2 * EMB) {
#pragma unroll
        for (int nt = 0; nt < 4; ++nt) {
            const int c  = n0 + wn + nt * 16 + l15;
            const float bv = bias[c];
            const int vcol = c - 2 * EMB;
            const int hh = vcol >> 6, dd = vcol & 63;
#pragma unroll
            for (int mt = 0; mt < MT; ++mt) {
                const int r = m0 + wm + mt * 16 + quad * 4;
                const int bb = r >> 11, ss = r & 2047;
                half4 o = { (_Float16)(acc[mt][nt][0] + bv), (_Float16)(acc[mt][nt][1] + bv),
                            (_Float16)(acc[mt][nt][2] + bv), (_Float16)(acc[mt][nt][3] + bv) };
                *(half4*)(vt + ((size_t)(bb * NH + hh) * HD + dd) * S_LEN + ss) = o;
            }
        }
        return;
    }

#pragma unroll
    for (int nt = 0; nt < 4; ++nt) {
        const int c = n0 + wn + nt * 16 + l15;
        const float bv = bias[c];
#pragma unroll
        for (int mt = 0; mt < MT; ++mt)
#pragma unroll
            for (int reg = 0; reg < 4; ++reg) {
                const int r = m0 + wm + mt * 16 + quad * 4 + reg;
                const float v = acc[mt][nt][reg] + bv;
                if (OUT_F16)
                    ((_Float16*)Cout)[(size_t)r * N + c] = (_Float16)v;
                else
                    ((float*)Cout)[(size_t)r * N + c] = v;
            }
    }
}

// ---------------------------------------------------------------------------
// MFMA flash attention v11: NO LDS, NO BARRIERS. K/V per bh (512 KB) is
// L2-resident by the XCD mapping (4 bh/XCD = 2 MB < 4 MiB L2); a tile's
// K+V (32 KB) fits L1. Fragments are read directly from global (catalog
// common-mistake #7: LDS-staging L2-fit data is pure overhead). Dual q-tile
// streams per block (v7 pairing): one kf/vf read feeds both softmax chains,
// uniform 17 k-tiles/block. Waves run free -- no lockstep, no vmcnt(0)
// drains, no bank conflicts; compiler schedules loads across tile bounds.
// ---------------------------------------------------------------------------
__global__ __launch_bounds__(256, 2)
void attn_fa_mfma11(const _Float16* __restrict__ qkv,
                    const _Float16* __restrict__ vt,
                    _Float16* __restrict__ outh)
{
    const int n   = blockIdx.x;
    const int xcd = n & 7, g = (n >> 3) & 3, j = n >> 5;
    const int bh  = xcd * 4 + g;
    const int qta = j, qtb = 31 - j;
    const int b = bh >> 4, h = bh & 15;

    const int tid  = threadIdx.x;
    const int wave = tid >> 6, lane = tid & 63;
    const int quad = lane >> 4, l15 = lane & 15;
    const size_t row0 = (size_t)b * S_LEN;

    const _Float16 qscale = (_Float16)0.0901684400555602f;
    half8 qfa[2], qfb[2];
    {
        const _Float16* qpa = qkv + (row0 + qta * 64 + wave * 16 + l15) * QKV_N + h * HD + quad * 8;
        const _Float16* qpb = qkv + (row0 + qtb * 64 + wave * 16 + l15) * QKV_N + h * HD + quad * 8;
#pragma unroll
        for (int c = 0; c < 2; ++c) {
            half8 qa = *(const half8*)(qpa + c * 32);
            half8 qb = *(const half8*)(qpb + c * 32);
#pragma unroll
            for (int j2 = 0; j2 < 8; ++j2) { qa[j2] *= qscale; qb[j2] *= qscale; }
            qfa[c] = qa; qfb[c] = qb;
        }
    }

    f32x4 o_a[4] = {}, o_b[4] = {};
    float m_a = -1e30f, l_a = 0.0f, m_b = -1e30f, l_b = 0.0f;

    const _Float16* vbase = vt + (size_t)bh * HD * S_LEN;

    // per-stream softmax + P pack (independent chains; inlined twice per tile)
    auto softmax_pack = [&](f32x4 (&st)[8], half4 (&pf)[8], float& m_i, float& l_i,
                            f32x4 (&o_acc)[4]) {
        float rm = fmaxf(fmaxf(st[0][0], st[0][1]), fmaxf(st[0][2], st[0][3]));
#pragma unroll
        for (int nt = 1; nt < 8; ++nt) {
            rm = fmaxf(rm, fmaxf(st[nt][0], st[nt][1]));
            rm = fmaxf(rm, fmaxf(st[nt][2], st[nt][3]));
        }
        rm = fmaxf(rm, __shfl_xor(rm, 16));
        rm = fmaxf(rm, __shfl_xor(rm, 32));
        const float mnew = fmaxf(m_i, rm);
        if (__ballot(mnew > m_i)) {
            const float alpha = __builtin_amdgcn_exp2f(m_i - mnew);
            l_i *= alpha;
#pragma unroll
            for (int dt = 0; dt < 4; ++dt)
#pragma unroll
                for (int reg = 0; reg < 4; ++reg) o_acc[dt][reg] *= alpha;
        }
        m_i = mnew;
        float rs = 0.0f;
#pragma unroll
        for (int nt = 0; nt < 8; ++nt) {
            float p0 = __builtin_amdgcn_exp2f(st[nt][0] - mnew);
            float p1 = __builtin_amdgcn_exp2f(st[nt][1] - mnew);
            float p2 = __builtin_amdgcn_exp2f(st[nt][2] - mnew);
            float p3 = __builtin_amdgcn_exp2f(st[nt][3] - mnew);
            rs += (p0 + p1) + (p2 + p3);
            pf[nt] = half4{ (_Float16)p0, (_Float16)p1, (_Float16)p2, (_Float16)p3 };
        }
        rs += __shfl_xor(rs, 16);
        rs += __shfl_xor(rs, 32);
        l_i += rs;
    };

    const int ktNa = (qta + 2) >> 1;
    const int ktNb = (qtb + 2) >> 1;     // = 17 - ktNa (pairs sum uniform)

    for (int kt = 0; kt < ktNb; ++kt) {
        // direct-global fragment bases for this k-tile
        const _Float16* kb = qkv + (row0 + kt * 128) * QKV_N + EMB + h * HD;
        const _Float16* vb = vbase + kt * 128;

        if (kt < ktNa) {
            // ---- dual-stream tile: shared kf/vf, interleaved chains ----
            f32x4 sa[8] = {}, sb[8] = {};
#pragma unroll
            for (int c = 0; c < 2; ++c)
#pragma unroll
                for (int nt = 0; nt < 8; ++nt) {
                    half8 kf = *(const half8*)(kb + (size_t)(nt * 16 + l15) * QKV_N + c * 32 + quad * 8);
                    sa[nt] = __builtin_amdgcn_mfma_f32_16x16x32_f16(kf, qfa[c], sa[nt], 0, 0, 0);
                    sb[nt] = __builtin_amdgcn_mfma_f32_16x16x32_f16(kf, qfb[c], sb[nt], 0, 0, 0);
                }
            if (kt == ktNa - 1) {          // mask stream A only (B is far from diag)
                const int q = qta * 64 + wave * 16 + l15;
#pragma unroll
                for (int nt = 0; nt < 8; ++nt) {
                    const int ks = kt * 128 + nt * 16 + quad * 4;
#pragma unroll
                    for (int reg = 0; reg < 4; ++reg)
                        if (ks + reg > q) sa[nt][reg] = -1e30f;
                }
            }
            half4 pfa[8], pfb[8];
            softmax_pack(sa, pfa, m_a, l_a, o_a);
            softmax_pack(sb, pfb, m_b, l_b, o_b);
#pragma unroll
            for (int nt = 0; nt < 8; ++nt)
#pragma unroll
                for (int dt = 0; dt < 4; ++dt) {
                    half4 vf = *(const half4*)(vb + (size_t)(dt * 16 + l15) * S_LEN
                                               + (2 * nt + (quad >> 1)) * 8 + (quad & 1) * 4);
                    o_a[dt] = __builtin_amdgcn_mfma_f32_16x16x16f16(vf, pfa[nt], o_a[dt], 0, 0, 0);
                    o_b[dt] = __builtin_amdgcn_mfma_f32_16x16x16f16(vf, pfb[nt], o_b[dt], 0, 0, 0);
                }
        } else {
            // ---- single-stream tile (B only) ----
            f32x4 sb[8] = {};
#pragma unroll
            for (int c = 0; c < 2; ++c)
#pragma unroll
                for (int nt = 0; nt < 8; ++nt) {
                    half8 kf = *(const half8*)(kb + (size_t)(nt * 16 + l15) * QKV_N + c * 32 + quad * 8);
                    sb[nt] = __builtin_amdgcn_mfma_f32_16x16x32_f16(kf, qfb[c], sb[nt], 0, 0, 0);
                }
            if (kt == ktNb - 1) {
                const int q = qtb * 64 + wave * 16 + l15;
#pragma unroll
                for (int nt = 0; nt < 8; ++nt) {
                    const int ks = kt * 128 + nt * 16 + quad * 4;
#pragma unroll
                    for (int reg = 0; reg < 4; ++reg)
                        if (ks + reg > q) sb[nt][reg] = -1e30f;
                }
            }
            half4 pfb[8];
            softmax_pack(sb, pfb, m_b, l_b, o_b);
#pragma unroll
            for (int nt = 0; nt < 8; ++nt)
#pragma unroll
                for (int dt = 0; dt < 4; ++dt) {
                    half4 vf = *(const half4*)(vb + (size_t)(dt * 16 + l15) * S_LEN
                                               + (2 * nt + (quad >> 1)) * 8 + (quad & 1) * 4);
                    o_b[dt] = __builtin_amdgcn_mfma_f32_16x16x16f16(vf, pfb[nt], o_b[dt], 0, 0, 0);
                }
        }
    }

    // ---- epilogues ----
    {
        const float inv = 1.0f / l_a;
        const size_t r = row0 + qta * 64 + wave * 16 + l15;
#pragma unroll
        for (int dt = 0; dt < 4; ++dt) {
            half4 o = { (_Float16)(o_a[dt][0] * inv), (_Float16)(o_a[dt][1] * inv),
                        (_Float16)(o_a[dt][2] * inv), (_Float16)(o_a[dt][3] * inv) };
            *(half4*)(outh + r * EMB + h * HD + dt * 16 + quad * 4) = o;
        }
    }
    {
        const float inv = 1.0f / l_b;
        const size_t r = row0 + qtb * 64 + wave * 16 + l15;
#pragma unroll
        for (int dt = 0; dt < 4; ++dt) {
            half4 o = { (_Float16)(o_b[dt][0] * inv), (_Float16)(o_b[dt][1] * inv),
                        (_Float16)(o_b[dt][2] * inv), (_Float16)(o_b[dt][3] * inv) };
            *(half4*)(outh + r * EMB + h * HD + dt * 16 + quad * 4) = o;
        }
    }
}

// ---------------------------------------------------------------------------
extern "C" void kernel_launch(void* const* d_in, const int* in_sizes, int n_in,
                              void* d_out, int out_size, void* d_ws, size_t ws_size,
                              hipStream_t stream)
{
    const float* hidden = (const float*)d_in[0];
    const float* w_attn = (const float*)d_in[1];
    const float* b_attn = (const float*)d_in[2];
    const float* w_proj = (const float*)d_in[3];
    const float* b_proj = (const float*)d_in[4];

    _Float16* hidden_h = (_Float16*)d_ws;                        // 4M
    _Float16* wattn_t  = hidden_h + (size_t)MROWS * EMB;         // 3M
    _Float16* wproj_t  = wattn_t + (size_t)EMB * QKV_N;          // 1M
    _Float16* qkv_h    = wproj_t + (size_t)EMB * EMB;            // 12M
    _Float16* attn_h   = qkv_h + (size_t)MROWS * QKV_N;          // 4M
    _Float16* vt       = attn_h + (size_t)MROWS * EMB;           // 4M

    prep_all<<<8192, 256, 0, stream>>>(hidden, w_attn, w_proj,
                                       hidden_h, wattn_t, wproj_t);

    hgemm_lds<4, 3, true, true><<<dim3(QKV_N / 128, MROWS / 128), 256, 0, stream>>>(
        hidden_h, wattn_t, b_attn, qkv_h, vt, MROWS, QKV_N, EMB);

    attn_fa_mfma11<<<dim3(512), 256, 0, stream>>>(qkv_h, vt, attn_h);

    hgemm_lds<2, 4, false, false><<<dim3(EMB / 128, MROWS / 64), 256, 0, stream>>>(
        attn_h, wproj_t, b_proj, d_out, nullptr, MROWS, EMB, EMB);
}

// Round 6
// 171.457 us; speedup vs baseline: 1.6906x; 1.6906x over previous
//
#include <hip/hip_runtime.h>
#include <cstddef>
#include <cstdint>

#define B_DIM   2
#define S_LEN   2048
#define EMB     1024
#define NH      16
#define HD      64
#define QKV_N   3072
#define MROWS   (B_DIM * S_LEN)

using half8  = __attribute__((ext_vector_type(8))) _Float16;
using half4  = __attribute__((ext_vector_type(4))) _Float16;
using f32x4  = __attribute__((ext_vector_type(4))) float;

#if defined(__has_builtin)
#if __has_builtin(__builtin_amdgcn_global_load_lds)
#define HAS_GLL 1
#endif
#endif

__device__ __forceinline__ void stage16(const _Float16* g, _Float16* lds_base, int lane)
{
#ifdef HAS_GLL
    (void)lane;
    __builtin_amdgcn_global_load_lds(
        (const __attribute__((address_space(1))) unsigned int*)g,
        (__attribute__((address_space(3))) unsigned int*)lds_base, 16, 0, 0);
#else
    *(half8*)(lds_base + lane * 8) = *(const half8*)g;
#endif
}

// ---------------------------------------------------------------------------
// Merged prep: [0,4096) cast hidden; [4096,7168) transpose w_attn;
// [7168,8192) transpose w_proj.
// ---------------------------------------------------------------------------
__global__ __launch_bounds__(256)
void prep_all(const float* __restrict__ hidden, const float* __restrict__ w_attn,
              const float* __restrict__ w_proj, _Float16* __restrict__ hidden_h,
              _Float16* __restrict__ wattn_t, _Float16* __restrict__ wproj_t)
{
    const int bid = blockIdx.x, t = threadIdx.x;
    if (bid < 4096) {
        int i = bid * 1024 + t * 4;
        float4 v = *(const float4*)(hidden + i);
        half4 h = { (_Float16)v.x, (_Float16)v.y, (_Float16)v.z, (_Float16)v.w };
        *(half4*)(hidden_h + i) = h;
        return;
    }
    __shared__ float T[32][33];
    const float* W; _Float16* Wt; int N, bx, by;
    if (bid < 7168) {
        int t2 = bid - 4096; bx = t2 % 96; by = t2 / 96; W = w_attn; Wt = wattn_t; N = QKV_N;
    } else {
        int t3 = bid - 7168; bx = t3 & 31; by = t3 >> 5; W = w_proj; Wt = wproj_t; N = EMB;
    }
    const int n0 = bx * 32, k0 = by * 32;
    const int r = t >> 3, c4 = (t & 7) * 4;
    float4 w = *(const float4*)(W + (size_t)(k0 + r) * N + n0 + c4);
    T[r][c4 + 0] = w.x; T[r][c4 + 1] = w.y;
    T[r][c4 + 2] = w.z; T[r][c4 + 3] = w.w;
    __syncthreads();
    half4 h = { (_Float16)T[c4 + 0][r], (_Float16)T[c4 + 1][r],
                (_Float16)T[c4 + 2][r], (_Float16)T[c4 + 3][r] };
    *(half4*)(Wt + (size_t)(n0 + r) * EMB + k0 + c4) = h;
}

// ---------------------------------------------------------------------------
// f16 MFMA GEMM, BK=64, GLL staging, XOR-swizzled LDS columns.
// FUSE_VT: blocks with n0 >= 2*EMB write V transposed into vt[bh][d][s].
// ---------------------------------------------------------------------------
template <int MT, int MINW, bool OUT_F16, bool FUSE_VT>
__global__ __launch_bounds__(256, MINW)
void hgemm_lds(const _Float16* __restrict__ X, const _Float16* __restrict__ Wt,
               const float* __restrict__ bias, void* __restrict__ Cout,
               _Float16* __restrict__ vt, int M, int N, int K)
{
    constexpr int BM = MT * 32;
    constexpr int ACALLS = BM / 32;
    __shared__ _Float16 As[BM][64];
    __shared__ _Float16 Bs[128][64];

    const int tid  = threadIdx.x;
    const int wave = tid >> 6, lane = tid & 63;
    const int quad = lane >> 4, l15 = lane & 15;
    const int wm = (wave >> 1) * (MT * 16);
    const int wn = (wave & 1) * 64;
    const int m0 = blockIdx.y * BM, n0 = blockIdx.x * 128;

    const int srow = lane >> 3;
    const int scol = ((lane & 7) ^ srow) * 8;

    const _Float16* xg[ACALLS];
#pragma unroll
    for (int c = 0; c < ACALLS; ++c)
        xg[c] = X + (size_t)(m0 + wave * (BM / 4) + c * 8 + srow) * K + scol;
    const _Float16* wg[4];
#pragma unroll
    for (int c = 0; c < 4; ++c)
        wg[c] = Wt + (size_t)(n0 + wave * 32 + c * 8 + srow) * K + scol;

    f32x4 acc[MT][4] = {};
    const int sx = l15 & 7;

    for (int k0 = 0; k0 < K; k0 += 64) {
#pragma unroll
        for (int c = 0; c < ACALLS; ++c)
            stage16(xg[c] + k0, &As[wave * (BM / 4) + c * 8][0], lane);
#pragma unroll
        for (int c = 0; c < 4; ++c)
            stage16(wg[c] + k0, &Bs[wave * 32 + c * 8][0], lane);
        __syncthreads();

#pragma unroll
        for (int cc = 0; cc < 2; ++cc) {
            half8 af[MT], bf[4];
#pragma unroll
            for (int mt = 0; mt < MT; ++mt)
                af[mt] = *(const half8*)&As[wm + mt * 16 + l15][(((cc * 4 + quad) ^ sx)) * 8];
#pragma unroll
            for (int nt = 0; nt < 4; ++nt)
                bf[nt] = *(const half8*)&Bs[wn + nt * 16 + l15][(((cc * 4 + quad) ^ sx)) * 8];
#pragma unroll
            for (int mt = 0; mt < MT; ++mt)
#pragma unroll
                for (int nt = 0; nt < 4; ++nt)
                    acc[mt][nt] = __builtin_amdgcn_mfma_f32_16x16x32_f16(
                        af[mt], bf[nt], acc[mt][nt], 0, 0, 0);
        }
        __syncthreads();
    }

    if (FUSE_VT && n0 >= 2 * EMB) {
#pragma unroll
        for (int nt = 0; nt < 4; ++nt) {
            const int c  = n0 + wn + nt * 16 + l15;
            const float bv = bias[c];
            const int vcol = c - 2 * EMB;
            const int hh = vcol >> 6, dd = vcol & 63;
#pragma unroll
            for (int mt = 0; mt < MT; ++mt) {
                const int r = m0 + wm + mt * 16 + quad * 4;
                const int bb = r >> 11, ss = r & 2047;
                half4 o = { (_Float16)(acc[mt][nt][0] + bv), (_Float16)(acc[mt][nt][1] + bv),
                            (_Float16)(acc[mt][nt][2] + bv), (_Float16)(acc[mt][nt][3] + bv) };
                *(half4*)(vt + ((size_t)(bb * NH + hh) * HD + dd) * S_LEN + ss) = o;
            }
        }
        return;
    }

#pragma unroll
    for (int nt = 0; nt < 4; ++nt) {
        const int c = n0 + wn + nt * 16 + l15;
        const float bv = bias[c];
#pragma unroll
        for (int mt = 0; mt < MT; ++mt)
#pragma unroll
            for (int reg = 0; reg < 4; ++reg) {
                const int r = m0 + wm + mt * 16 + quad * 4 + reg;
                const float v = acc[mt][nt][reg] + bv;
                if (OUT_F16)
                    ((_Float16*)Cout)[(size_t)r * N + c] = (_Float16)v;
                else
                    ((float*)Cout)[(size_t)r * N + c] = v;
            }
    }
}

// ---------------------------------------------------------------------------
// MFMA flash attention v12 = v7 (best-known structure: paired complementary
// q-tiles, single-buffered LDS, two barriers/tile) + T13 defer-max: skip the
// O/l rescale while per-tile max growth <= 8 (log2 units, since qscale folds
// log2e). P bounded by 2^8=256 -- safe in f16; the stale-max scale cancels at
// the final 1/l normalize. Kills most rescale VALU passes and shortens the
// serial softmax chain between QK and PV MFMA clusters.
// ---------------------------------------------------------------------------
__global__ __launch_bounds__(256, 2)
void attn_fa_mfma12(const _Float16* __restrict__ qkv,
                    const _Float16* __restrict__ vt,
                    _Float16* __restrict__ outh)
{
    __shared__ _Float16 Ks[128][64];
    __shared__ _Float16 Vs[64][128];

    const int n   = blockIdx.x;
    const int xcd = n & 7, g = (n >> 3) & 3, j = n >> 5;
    const int bh  = xcd * 4 + g;
    const int qta = j, qtb = 31 - j;
    const int b = bh >> 4, h = bh & 15;

    const int tid  = threadIdx.x;
    const int wave = tid >> 6, lane = tid & 63;
    const int quad = lane >> 4, l15 = lane & 15;
    const size_t row0 = (size_t)b * S_LEN;

    const _Float16 qscale = (_Float16)0.0901684400555602f;
    half8 qfa[2], qfb[2];
    {
        const _Float16* qpa = qkv + (row0 + qta * 64 + wave * 16 + l15) * QKV_N + h * HD + quad * 8;
        const _Float16* qpb = qkv + (row0 + qtb * 64 + wave * 16 + l15) * QKV_N + h * HD + quad * 8;
#pragma unroll
        for (int c = 0; c < 2; ++c) {
            half8 qa = *(const half8*)(qpa + c * 32);
            half8 qb = *(const half8*)(qpb + c * 32);
#pragma unroll
            for (int j2 = 0; j2 < 8; ++j2) { qa[j2] *= qscale; qb[j2] *= qscale; }
            qfa[c] = qa; qfb[c] = qb;
        }
    }

    f32x4 o_a[4] = {}, o_b[4] = {};
    float m_a = -1e30f, l_a = 0.0f, m_b = -1e30f, l_b = 0.0f;

    const int ksrow = lane >> 3;
    const int kscol = ((lane & 7) ^ ksrow) * 8;
    const int vsrow = lane >> 4;
    const _Float16* vbase = vt + (size_t)bh * HD * S_LEN;
    const int sxk = l15 & 7;

    // per-stream softmax + P pack with T13 defer-max (THR=8 in log2 units)
    auto softmax_pack = [&](f32x4 (&st)[8], half4 (&pf)[8], float& m_i, float& l_i,
                            f32x4 (&o_acc)[4]) {
        float rm = fmaxf(fmaxf(st[0][0], st[0][1]), fmaxf(st[0][2], st[0][3]));
#pragma unroll
        for (int nt = 1; nt < 8; ++nt) {
            rm = fmaxf(rm, fmaxf(st[nt][0], st[nt][1]));
            rm = fmaxf(rm, fmaxf(st[nt][2], st[nt][3]));
        }
        rm = fmaxf(rm, __shfl_xor(rm, 16));
        rm = fmaxf(rm, __shfl_xor(rm, 32));
        // T13: only rescale when some row's max grew by more than THR.
        // Otherwise keep stale m_i; P bounded by exp2(THR)=256 (f16-safe).
        if (!__all(rm - m_i <= 8.0f)) {
            const float mnew = fmaxf(m_i, rm);
            const float alpha = __builtin_amdgcn_exp2f(m_i - mnew);
            l_i *= alpha;
#pragma unroll
            for (int dt = 0; dt < 4; ++dt)
#pragma unroll
                for (int reg = 0; reg < 4; ++reg) o_acc[dt][reg] *= alpha;
            m_i = mnew;
        }
        float rs = 0.0f;
#pragma unroll
        for (int nt = 0; nt < 8; ++nt) {
            float p0 = __builtin_amdgcn_exp2f(st[nt][0] - m_i);
            float p1 = __builtin_amdgcn_exp2f(st[nt][1] - m_i);
            float p2 = __builtin_amdgcn_exp2f(st[nt][2] - m_i);
            float p3 = __builtin_amdgcn_exp2f(st[nt][3] - m_i);
            rs += (p0 + p1) + (p2 + p3);
            pf[nt] = half4{ (_Float16)p0, (_Float16)p1, (_Float16)p2, (_Float16)p3 };
        }
        rs += __shfl_xor(rs, 16);
        rs += __shfl_xor(rs, 32);
        l_i += rs;
    };

    const int ktNa = (qta + 2) >> 1;
    const int ktNb = (qtb + 2) >> 1;     // = 17 - ktNa (pairs sum uniform)

    for (int kt = 0; kt < ktNb; ++kt) {
        __syncthreads();
        {
            const _Float16* kbase = qkv + (row0 + kt * 128) * QKV_N + EMB + h * HD;
#pragma unroll
            for (int c = 0; c < 4; ++c) {
                const int r0 = wave * 32 + c * 8;
                stage16(kbase + (size_t)(r0 + ksrow) * QKV_N + kscol, &Ks[r0][0], lane);
            }
#pragma unroll
            for (int c = 0; c < 4; ++c) {
                const int r0 = wave * 16 + c * 4;
                const int sgv = ((lane & 15) ^ (c * 4 + vsrow)) * 8;
                stage16(vbase + (size_t)(r0 + vsrow) * S_LEN + kt * 128 + sgv, &Vs[r0][0], lane);
            }
        }
        __syncthreads();

        if (kt < ktNa) {
            // ---- dual-stream tile: shared kf/vf, interleaved chains ----
            f32x4 sa[8] = {}, sb[8] = {};
#pragma unroll
            for (int c = 0; c < 2; ++c)
#pragma unroll
                for (int nt = 0; nt < 8; ++nt) {
                    half8 kf = *(const half8*)&Ks[nt * 16 + l15][((c * 4 + quad) ^ sxk) * 8];
                    sa[nt] = __builtin_amdgcn_mfma_f32_16x16x32_f16(kf, qfa[c], sa[nt], 0, 0, 0);
                    sb[nt] = __builtin_amdgcn_mfma_f32_16x16x32_f16(kf, qfb[c], sb[nt], 0, 0, 0);
                }
            if (kt == ktNa - 1) {          // mask stream A only (B is far from diag)
                const int q = qta * 64 + wave * 16 + l15;
#pragma unroll
                for (int nt = 0; nt < 8; ++nt) {
                    const int ks = kt * 128 + nt * 16 + quad * 4;
#pragma unroll
                    for (int reg = 0; reg < 4; ++reg)
                        if (ks + reg > q) sa[nt][reg] = -1e30f;
                }
            }
            half4 pfa[8], pfb[8];
            softmax_pack(sa, pfa, m_a, l_a, o_a);
            softmax_pack(sb, pfb, m_b, l_b, o_b);
#pragma unroll
            for (int nt = 0; nt < 8; ++nt)
#pragma unroll
                for (int dt = 0; dt < 4; ++dt) {
                    const int pg = ((2 * nt + (quad >> 1)) ^ l15) * 8 + (quad & 1) * 4;
                    half4 vf = *(const half4*)&Vs[dt * 16 + l15][pg];
                    o_a[dt] = __builtin_amdgcn_mfma_f32_16x16x16f16(vf, pfa[nt], o_a[dt], 0, 0, 0);
                    o_b[dt] = __builtin_amdgcn_mfma_f32_16x16x16f16(vf, pfb[nt], o_b[dt], 0, 0, 0);
                }
        } else {
            // ---- single-stream tile (B only) ----
            f32x4 sb[8] = {};
#pragma unroll
            for (int c = 0; c < 2; ++c)
#pragma unroll
                for (int nt = 0; nt < 8; ++nt) {
                    half8 kf = *(const half8*)&Ks[nt * 16 + l15][((c * 4 + quad) ^ sxk) * 8];
                    sb[nt] = __builtin_amdgcn_mfma_f32_16x16x32_f16(kf, qfb[c], sb[nt], 0, 0, 0);
                }
            if (kt == ktNb - 1) {
                const int q = qtb * 64 + wave * 16 + l15;
#pragma unroll
                for (int nt = 0; nt < 8; ++nt) {
                    const int ks = kt * 128 + nt * 16 + quad * 4;
#pragma unroll
                    for (int reg = 0; reg < 4; ++reg)
                        if (ks + reg > q) sb[nt][reg] = -1e30f;
                }
            }
            half4 pfb[8];
            softmax_pack(sb, pfb, m_b, l_b, o_b);
#pragma unroll
            for (int nt = 0; nt < 8; ++nt)
#pragma unroll
                for (int dt = 0; dt < 4; ++dt) {
                    const int pg = ((2 * nt + (quad >> 1)) ^ l15) * 8 + (quad & 1) * 4;
                    half4 vf = *(const half4*)&Vs[dt * 16 + l15][pg];
                    o_b[dt] = __builtin_amdgcn_mfma_f32_16x16x16f16(vf, pfb[nt], o_b[dt], 0, 0, 0);
                }
        }
    }

    // ---- epilogues ----
    {
        const float inv = 1.0f / l_a;
        const size_t r = row0 + qta * 64 + wave * 16 + l15;
#pragma unroll
        for (int dt = 0; dt < 4; ++dt) {
            half4 o = { (_Float16)(o_a[dt][0] * inv), (_Float16)(o_a[dt][1] * inv),
                        (_Float16)(o_a[dt][2] * inv), (_Float16)(o_a[dt][3] * inv) };
            *(half4*)(outh + r * EMB + h * HD + dt * 16 + quad * 4) = o;
        }
    }
    {
        const float inv = 1.0f / l_b;
        const size_t r = row0 + qtb * 64 + wave * 16 + l15;
#pragma unroll
        for (int dt = 0; dt < 4; ++dt) {
            half4 o = { (_Float16)(o_b[dt][0] * inv), (_Float16)(o_b[dt][1] * inv),
                        (_Float16)(o_b[dt][2] * inv), (_Float16)(o_b[dt][3] * inv) };
            *(half4*)(outh + r * EMB + h * HD + dt * 16 + quad * 4) = o;
        }
    }
}

// ---------------------------------------------------------------------------
extern "C" void kernel_launch(void* const* d_in, const int* in_sizes, int n_in,
                              void* d_out, int out_size, void* d_ws, size_t ws_size,
                              hipStream_t stream)
{
    const float* hidden = (const float*)d_in[0];
    const float* w_attn = (const float*)d_in[1];
    const float* b_attn = (const float*)d_in[2];
    const float* w_proj = (const float*)d_in[3];
    const float* b_proj = (const float*)d_in[4];

    _Float16* hidden_h = (_Float16*)d_ws;                        // 4M
    _Float16* wattn_t  = hidden_h + (size_t)MROWS * EMB;         // 3M
    _Float16* wproj_t  = wattn_t + (size_t)EMB * QKV_N;          // 1M
    _Float16* qkv_h    = wproj_t + (size_t)EMB * EMB;            // 12M
    _Float16* attn_h   = qkv_h + (size_t)MROWS * QKV_N;          // 4M
    _Float16* vt       = attn_h + (size_t)MROWS * EMB;           // 4M

    prep_all<<<8192, 256, 0, stream>>>(hidden, w_attn, w_proj,
                                       hidden_h, wattn_t, wproj_t);

    hgemm_lds<4, 3, true, true><<<dim3(QKV_N / 128, MROWS / 128), 256, 0, stream>>>(
        hidden_h, wattn_t, b_attn, qkv_h, vt, MROWS, QKV_N, EMB);

    attn_fa_mfma12<<<dim3(512), 256, 0, stream>>>(qkv_h, vt, attn_h);

    hgemm_lds<2, 4, false, false><<<dim3(EMB / 128, MROWS / 64), 256, 0, stream>>>(
        attn_h, wproj_t, b_proj, d_out, nullptr, MROWS, EMB, EMB);
}

// Round 9
// 166.034 us; speedup vs baseline: 1.7458x; 1.0327x over previous
//
#include <hip/hip_runtime.h>
#include <cstddef>
#include <cstdint>

#define B_DIM   2
#define S_LEN   2048
#define EMB     1024
#define NH      16
#define HD      64
#define QKV_N   3072
#define MROWS   (B_DIM * S_LEN)

using half8  = __attribute__((ext_vector_type(8))) _Float16;
using half4  = __attribute__((ext_vector_type(4))) _Float16;
using fp16x2 = __attribute__((ext_vector_type(2))) __fp16;   // return type of cvt_pkrtz
using f32x4  = __attribute__((ext_vector_type(4))) float;

#if defined(__has_builtin)
#if __has_builtin(__builtin_amdgcn_global_load_lds)
#define HAS_GLL 1
#endif
#endif

__device__ __forceinline__ void stage16(const _Float16* g, _Float16* lds_base, int lane)
{
#ifdef HAS_GLL
    (void)lane;
    __builtin_amdgcn_global_load_lds(
        (const __attribute__((address_space(1))) unsigned int*)g,
        (__attribute__((address_space(3))) unsigned int*)lds_base, 16, 0, 0);
#else
    *(half8*)(lds_base + lane * 8) = *(const half8*)g;
#endif
}

// ---------------------------------------------------------------------------
// Merged prep: [0,4096) cast hidden; [4096,7168) transpose w_attn;
// [7168,8192) transpose w_proj.
// ---------------------------------------------------------------------------
__global__ __launch_bounds__(256)
void prep_all(const float* __restrict__ hidden, const float* __restrict__ w_attn,
              const float* __restrict__ w_proj, _Float16* __restrict__ hidden_h,
              _Float16* __restrict__ wattn_t, _Float16* __restrict__ wproj_t)
{
    const int bid = blockIdx.x, t = threadIdx.x;
    if (bid < 4096) {
        int i = bid * 1024 + t * 4;
        float4 v = *(const float4*)(hidden + i);
        half4 h = { (_Float16)v.x, (_Float16)v.y, (_Float16)v.z, (_Float16)v.w };
        *(half4*)(hidden_h + i) = h;
        return;
    }
    __shared__ float T[32][33];
    const float* W; _Float16* Wt; int N, bx, by;
    if (bid < 7168) {
        int t2 = bid - 4096; bx = t2 % 96; by = t2 / 96; W = w_attn; Wt = wattn_t; N = QKV_N;
    } else {
        int t3 = bid - 7168; bx = t3 & 31; by = t3 >> 5; W = w_proj; Wt = wproj_t; N = EMB;
    }
    const int n0 = bx * 32, k0 = by * 32;
    const int r = t >> 3, c4 = (t & 7) * 4;
    float4 w = *(const float4*)(W + (size_t)(k0 + r) * N + n0 + c4);
    T[r][c4 + 0] = w.x; T[r][c4 + 1] = w.y;
    T[r][c4 + 2] = w.z; T[r][c4 + 3] = w.w;
    __syncthreads();
    half4 h = { (_Float16)T[c4 + 0][r], (_Float16)T[c4 + 1][r],
                (_Float16)T[c4 + 2][r], (_Float16)T[c4 + 3][r] };
    *(half4*)(Wt + (size_t)(n0 + r) * EMB + k0 + c4) = h;
}

// ---------------------------------------------------------------------------
// f16 MFMA GEMM, BK=64, GLL staging, XOR-swizzled LDS columns.
// FUSE_VT: blocks with n0 >= 2*EMB write V transposed into vt[bh][d][s].
// ---------------------------------------------------------------------------
template <int MT, int MINW, bool OUT_F16, bool FUSE_VT>
__global__ __launch_bounds__(256, MINW)
void hgemm_lds(const _Float16* __restrict__ X, const _Float16* __restrict__ Wt,
               const float* __restrict__ bias, void* __restrict__ Cout,
               _Float16* __restrict__ vt, int M, int N, int K)
{
    constexpr int BM = MT * 32;
    constexpr int ACALLS = BM / 32;
    __shared__ _Float16 As[BM][64];
    __shared__ _Float16 Bs[128][64];

    const int tid  = threadIdx.x;
    const int wave = tid >> 6, lane = tid & 63;
    const int quad = lane >> 4, l15 = lane & 15;
    const int wm = (wave >> 1) * (MT * 16);
    const int wn = (wave & 1) * 64;
    const int m0 = blockIdx.y * BM, n0 = blockIdx.x * 128;

    const int srow = lane >> 3;
    const int scol = ((lane & 7) ^ srow) * 8;

    const _Float16* xg[ACALLS];
#pragma unroll
    for (int c = 0; c < ACALLS; ++c)
        xg[c] = X + (size_t)(m0 + wave * (BM / 4) + c * 8 + srow) * K + scol;
    const _Float16* wg[4];
#pragma unroll
    for (int c = 0; c < 4; ++c)
        wg[c] = Wt + (size_t)(n0 + wave * 32 + c * 8 + srow) * K + scol;

    f32x4 acc[MT][4] = {};
    const int sx = l15 & 7;

    for (int k0 = 0; k0 < K; k0 += 64) {
#pragma unroll
        for (int c = 0; c < ACALLS; ++c)
            stage16(xg[c] + k0, &As[wave * (BM / 4) + c * 8][0], lane);
#pragma unroll
        for (int c = 0; c < 4; ++c)
            stage16(wg[c] + k0, &Bs[wave * 32 + c * 8][0], lane);
        __syncthreads();

#pragma unroll
        for (int cc = 0; cc < 2; ++cc) {
            half8 af[MT], bf[4];
#pragma unroll
            for (int mt = 0; mt < MT; ++mt)
                af[mt] = *(const half8*)&As[wm + mt * 16 + l15][(((cc * 4 + quad) ^ sx)) * 8];
#pragma unroll
            for (int nt = 0; nt < 4; ++nt)
                bf[nt] = *(const half8*)&Bs[wn + nt * 16 + l15][(((cc * 4 + quad) ^ sx)) * 8];
#pragma unroll
            for (int mt = 0; mt < MT; ++mt)
#pragma unroll
                for (int nt = 0; nt < 4; ++nt)
                    acc[mt][nt] = __builtin_amdgcn_mfma_f32_16x16x32_f16(
                        af[mt], bf[nt], acc[mt][nt], 0, 0, 0);
        }
        __syncthreads();
    }

    if (FUSE_VT && n0 >= 2 * EMB) {
#pragma unroll
        for (int nt = 0; nt < 4; ++nt) {
            const int c  = n0 + wn + nt * 16 + l15;
            const float bv = bias[c];
            const int vcol = c - 2 * EMB;
            const int hh = vcol >> 6, dd = vcol & 63;
#pragma unroll
            for (int mt = 0; mt < MT; ++mt) {
                const int r = m0 + wm + mt * 16 + quad * 4;
                const int bb = r >> 11, ss = r & 2047;
                half4 o = { (_Float16)(acc[mt][nt][0] + bv), (_Float16)(acc[mt][nt][1] + bv),
                            (_Float16)(acc[mt][nt][2] + bv), (_Float16)(acc[mt][nt][3] + bv) };
                *(half4*)(vt + ((size_t)(bb * NH + hh) * HD + dd) * S_LEN + ss) = o;
            }
        }
        return;
    }

#pragma unroll
    for (int nt = 0; nt < 4; ++nt) {
        const int c = n0 + wn + nt * 16 + l15;
        const float bv = bias[c];
#pragma unroll
        for (int mt = 0; mt < MT; ++mt)
#pragma unroll
            for (int reg = 0; reg < 4; ++reg) {
                const int r = m0 + wm + mt * 16 + quad * 4 + reg;
                const float v = acc[mt][nt][reg] + bv;
                if (OUT_F16)
                    ((_Float16*)Cout)[(size_t)r * N + c] = (_Float16)v;
                else
                    ((float*)Cout)[(size_t)r * N + c] = v;
            }
    }
}

// ---------------------------------------------------------------------------
// MFMA flash attention v13b = v12 (v7 structure + T13 defer-max) +
//  - T17: max3-fusable fmax tree for the row-max reduction
//  - v_cvt_pkrtz_f16_f32 P-pack (fp16x2 receiver type; __fp16 -> _Float16
//    element casts are no-ops on amdgcn).
// ---------------------------------------------------------------------------
__global__ __launch_bounds__(256, 2)
void attn_fa_mfma13(const _Float16* __restrict__ qkv,
                    const _Float16* __restrict__ vt,
                    _Float16* __restrict__ outh)
{
    __shared__ _Float16 Ks[128][64];
    __shared__ _Float16 Vs[64][128];

    const int n   = blockIdx.x;
    const int xcd = n & 7, g = (n >> 3) & 3, j = n >> 5;
    const int bh  = xcd * 4 + g;
    const int qta = j, qtb = 31 - j;
    const int b = bh >> 4, h = bh & 15;

    const int tid  = threadIdx.x;
    const int wave = tid >> 6, lane = tid & 63;
    const int quad = lane >> 4, l15 = lane & 15;
    const size_t row0 = (size_t)b * S_LEN;

    const _Float16 qscale = (_Float16)0.0901684400555602f;
    half8 qfa[2], qfb[2];
    {
        const _Float16* qpa = qkv + (row0 + qta * 64 + wave * 16 + l15) * QKV_N + h * HD + quad * 8;
        const _Float16* qpb = qkv + (row0 + qtb * 64 + wave * 16 + l15) * QKV_N + h * HD + quad * 8;
#pragma unroll
        for (int c = 0; c < 2; ++c) {
            half8 qa = *(const half8*)(qpa + c * 32);
            half8 qb = *(const half8*)(qpb + c * 32);
#pragma unroll
            for (int j2 = 0; j2 < 8; ++j2) { qa[j2] *= qscale; qb[j2] *= qscale; }
            qfa[c] = qa; qfb[c] = qb;
        }
    }

    f32x4 o_a[4] = {}, o_b[4] = {};
    float m_a = -1e30f, l_a = 0.0f, m_b = -1e30f, l_b = 0.0f;

    const int ksrow = lane >> 3;
    const int kscol = ((lane & 7) ^ ksrow) * 8;
    const int vsrow = lane >> 4;
    const _Float16* vbase = vt + (size_t)bh * HD * S_LEN;
    const int sxk = l15 & 7;

    // per-stream softmax + P pack: T13 defer-max + max3 tree + pkrtz pack
    auto softmax_pack = [&](f32x4 (&st)[8], half4 (&pf)[8], float& m_i, float& l_i,
                            f32x4 (&o_acc)[4]) {
        float rm4[8];
#pragma unroll
        for (int nt = 0; nt < 8; ++nt) {
            const float t01 = fmaxf(st[nt][0], st[nt][1]);
            rm4[nt] = fmaxf(fmaxf(t01, st[nt][2]), st[nt][3]);   // -> v_max + v_max3
        }
        float rm = fmaxf(fmaxf(fmaxf(rm4[0], rm4[1]), fmaxf(rm4[2], rm4[3])),
                         fmaxf(fmaxf(rm4[4], rm4[5]), fmaxf(rm4[6], rm4[7])));
        rm = fmaxf(rm, __shfl_xor(rm, 16));
        rm = fmaxf(rm, __shfl_xor(rm, 32));
        // T13: only rescale when some row's max grew by more than THR=8.
        if (!__all(rm - m_i <= 8.0f)) {
            const float mnew = fmaxf(m_i, rm);
            const float alpha = __builtin_amdgcn_exp2f(m_i - mnew);
            l_i *= alpha;
#pragma unroll
            for (int dt = 0; dt < 4; ++dt)
#pragma unroll
                for (int reg = 0; reg < 4; ++reg) o_acc[dt][reg] *= alpha;
            m_i = mnew;
        }
        float rs = 0.0f;
#pragma unroll
        for (int nt = 0; nt < 8; ++nt) {
            const float p0 = __builtin_amdgcn_exp2f(st[nt][0] - m_i);
            const float p1 = __builtin_amdgcn_exp2f(st[nt][1] - m_i);
            const float p2 = __builtin_amdgcn_exp2f(st[nt][2] - m_i);
            const float p3 = __builtin_amdgcn_exp2f(st[nt][3] - m_i);
            rs += (p0 + p1) + (p2 + p3);
            const fp16x2 lo = __builtin_amdgcn_cvt_pkrtz(p0, p1);
            const fp16x2 hi = __builtin_amdgcn_cvt_pkrtz(p2, p3);
            pf[nt] = half4{ (_Float16)lo[0], (_Float16)lo[1],
                            (_Float16)hi[0], (_Float16)hi[1] };
        }
        rs += __shfl_xor(rs, 16);
        rs += __shfl_xor(rs, 32);
        l_i += rs;
    };

    const int ktNa = (qta + 2) >> 1;
    const int ktNb = (qtb + 2) >> 1;     // = 17 - ktNa (pairs sum uniform)

    for (int kt = 0; kt < ktNb; ++kt) {
        __syncthreads();
        {
            const _Float16* kbase = qkv + (row0 + kt * 128) * QKV_N + EMB + h * HD;
#pragma unroll
            for (int c = 0; c < 4; ++c) {
                const int r0 = wave * 32 + c * 8;
                stage16(kbase + (size_t)(r0 + ksrow) * QKV_N + kscol, &Ks[r0][0], lane);
            }
#pragma unroll
            for (int c = 0; c < 4; ++c) {
                const int r0 = wave * 16 + c * 4;
                const int sgv = ((lane & 15) ^ (c * 4 + vsrow)) * 8;
                stage16(vbase + (size_t)(r0 + vsrow) * S_LEN + kt * 128 + sgv, &Vs[r0][0], lane);
            }
        }
        __syncthreads();

        if (kt < ktNa) {
            // ---- dual-stream tile: shared kf/vf, interleaved chains ----
            f32x4 sa[8] = {}, sb[8] = {};
#pragma unroll
            for (int c = 0; c < 2; ++c)
#pragma unroll
                for (int nt = 0; nt < 8; ++nt) {
                    half8 kf = *(const half8*)&Ks[nt * 16 + l15][((c * 4 + quad) ^ sxk) * 8];
                    sa[nt] = __builtin_amdgcn_mfma_f32_16x16x32_f16(kf, qfa[c], sa[nt], 0, 0, 0);
                    sb[nt] = __builtin_amdgcn_mfma_f32_16x16x32_f16(kf, qfb[c], sb[nt], 0, 0, 0);
                }
            if (kt == ktNa - 1) {          // mask stream A only (B is far from diag)
                const int q = qta * 64 + wave * 16 + l15;
#pragma unroll
                for (int nt = 0; nt < 8; ++nt) {
                    const int ks = kt * 128 + nt * 16 + quad * 4;
#pragma unroll
                    for (int reg = 0; reg < 4; ++reg)
                        if (ks + reg > q) sa[nt][reg] = -1e30f;
                }
            }
            half4 pfa[8], pfb[8];
            softmax_pack(sa, pfa, m_a, l_a, o_a);
            softmax_pack(sb, pfb, m_b, l_b, o_b);
#pragma unroll
            for (int nt = 0; nt < 8; ++nt)
#pragma unroll
                for (int dt = 0; dt < 4; ++dt) {
                    const int pg = ((2 * nt + (quad >> 1)) ^ l15) * 8 + (quad & 1) * 4;
                    half4 vf = *(const half4*)&Vs[dt * 16 + l15][pg];
                    o_a[dt] = __builtin_amdgcn_mfma_f32_16x16x16f16(vf, pfa[nt], o_a[dt], 0, 0, 0);
                    o_b[dt] = __builtin_amdgcn_mfma_f32_16x16x16f16(vf, pfb[nt], o_b[dt], 0, 0, 0);
                }
        } else {
            // ---- single-stream tile (B only) ----
            f32x4 sb[8] = {};
#pragma unroll
            for (int c = 0; c < 2; ++c)
#pragma unroll
                for (int nt = 0; nt < 8; ++nt) {
                    half8 kf = *(const half8*)&Ks[nt * 16 + l15][((c * 4 + quad) ^ sxk) * 8];
                    sb[nt] = __builtin_amdgcn_mfma_f32_16x16x32_f16(kf, qfb[c], sb[nt], 0, 0, 0);
                }
            if (kt == ktNb - 1) {
                const int q = qtb * 64 + wave * 16 + l15;
#pragma unroll
                for (int nt = 0; nt < 8; ++nt) {
                    const int ks = kt * 128 + nt * 16 + quad * 4;
#pragma unroll
                    for (int reg = 0; reg < 4; ++reg)
                        if (ks + reg > q) sb[nt][reg] = -1e30f;
                }
            }
            half4 pfb[8];
            softmax_pack(sb, pfb, m_b, l_b, o_b);
#pragma unroll
            for (int nt = 0; nt < 8; ++nt)
#pragma unroll
                for (int dt = 0; dt < 4; ++dt) {
                    const int pg = ((2 * nt + (quad >> 1)) ^ l15) * 8 + (quad & 1) * 4;
                    half4 vf = *(const half4*)&Vs[dt * 16 + l15][pg];
                    o_b[dt] = __builtin_amdgcn_mfma_f32_16x16x16f16(vf, pfb[nt], o_b[dt], 0, 0, 0);
                }
        }
    }

    // ---- epilogues (pkrtz pack) ----
    {
        const float inv = 1.0f / l_a;
        const size_t r = row0 + qta * 64 + wave * 16 + l15;
#pragma unroll
        for (int dt = 0; dt < 4; ++dt) {
            const fp16x2 e01 = __builtin_amdgcn_cvt_pkrtz(o_a[dt][0] * inv, o_a[dt][1] * inv);
            const fp16x2 e23 = __builtin_amdgcn_cvt_pkrtz(o_a[dt][2] * inv, o_a[dt][3] * inv);
            half4 o = { (_Float16)e01[0], (_Float16)e01[1],
                        (_Float16)e23[0], (_Float16)e23[1] };
            *(half4*)(outh + r * EMB + h * HD + dt * 16 + quad * 4) = o;
        }
    }
    {
        const float inv = 1.0f / l_b;
        const size_t r = row0 + qtb * 64 + wave * 16 + l15;
#pragma unroll
        for (int dt = 0; dt < 4; ++dt) {
            const fp16x2 e01 = __builtin_amdgcn_cvt_pkrtz(o_b[dt][0] * inv, o_b[dt][1] * inv);
            const fp16x2 e23 = __builtin_amdgcn_cvt_pkrtz(o_b[dt][2] * inv, o_b[dt][3] * inv);
            half4 o = { (_Float16)e01[0], (_Float16)e01[1],
                        (_Float16)e23[0], (_Float16)e23[1] };
            *(half4*)(outh + r * EMB + h * HD + dt * 16 + quad * 4) = o;
        }
    }
}

// ---------------------------------------------------------------------------
extern "C" void kernel_launch(void* const* d_in, const int* in_sizes, int n_in,
                              void* d_out, int out_size, void* d_ws, size_t ws_size,
                              hipStream_t stream)
{
    const float* hidden = (const float*)d_in[0];
    const float* w_attn = (const float*)d_in[1];
    const float* b_attn = (const float*)d_in[2];
    const float* w_proj = (const float*)d_in[3];
    const float* b_proj = (const float*)d_in[4];

    _Float16* hidden_h = (_Float16*)d_ws;                        // 4M
    _Float16* wattn_t  = hidden_h + (size_t)MROWS * EMB;         // 3M
    _Float16* wproj_t  = wattn_t + (size_t)EMB * QKV_N;          // 1M
    _Float16* qkv_h    = wproj_t + (size_t)EMB * EMB;            // 12M
    _Float16* attn_h   = qkv_h + (size_t)MROWS * QKV_N;          // 4M
    _Float16* vt       = attn_h + (size_t)MROWS * EMB;           // 4M

    prep_all<<<8192, 256, 0, stream>>>(hidden, w_attn, w_proj,
                                       hidden_h, wattn_t, wproj_t);

    hgemm_lds<4, 3, true, true><<<dim3(QKV_N / 128, MROWS / 128), 256, 0, stream>>>(
        hidden_h, wattn_t, b_attn, qkv_h, vt, MROWS, QKV_N, EMB);

    attn_fa_mfma13<<<dim3(512), 256, 0, stream>>>(qkv_h, vt, attn_h);

    hgemm_lds<2, 4, false, false><<<dim3(EMB / 128, MROWS / 64), 256, 0, stream>>>(
        attn_h, wproj_t, b_proj, d_out, nullptr, MROWS, EMB, EMB);
}